// Round 6
// baseline (905.854 us; speedup 1.0000x reference)
//
#include <hip/hip_runtime.h>
#include <math.h>

// GraphSAGE: N=100k nodes, E=1.6M edges, IN=64, H0=H1=128, H2=256, OUT=40
// Pipeline: CSR build -> agg1 -> gemm1(sigmoid) -> agg2 -> gemm2(sigmoid)
//           -> mlp1(relu) -> mlp2(none)

// ---------------- edge dtype probe (int32 vs int64) ----------------
__global__ __launch_bounds__(64) void k_detect(const void* edges, int* flag) {
    if (threadIdx.x == 0 && blockIdx.x == 0) {
        const int* w = (const int*)edges;
        int o = 0;
        for (int i = 1; i < 128; i += 2) o |= w[i];  // int64 => high words all 0
        *flag = (o == 0) ? 1 : 0;
    }
}

__device__ __forceinline__ int edge_at(const void* p, int is64, size_t idx) {
    return is64 ? (int)((const long long*)p)[idx] : ((const int*)p)[idx];
}

// ---------------- degree histogram ----------------
__global__ __launch_bounds__(256) void k_hist(const void* edges, const int* flag,
                                              int E, int* deg) {
    int is64 = *flag;
    for (int e = blockIdx.x * blockDim.x + threadIdx.x; e < E;
         e += gridDim.x * blockDim.x) {
        int d = edge_at(edges, is64, (size_t)E + e);
        atomicAdd(&deg[d], 1);
    }
}

// ---------------- scan (3-kernel exclusive scan over n entries) ----------------
__global__ __launch_bounds__(256) void k_scan_a(const int* __restrict__ deg,
                                                int* __restrict__ bsum, int n) {
    __shared__ int sh[256];
    int base = blockIdx.x * 1024;
    int t = threadIdx.x;
    int s = 0;
#pragma unroll
    for (int i = 0; i < 4; ++i) {
        int idx = base + t * 4 + i;
        if (idx < n) s += deg[idx];
    }
    sh[t] = s;
    __syncthreads();
    for (int off = 128; off > 0; off >>= 1) {
        if (t < off) sh[t] += sh[t + off];
        __syncthreads();
    }
    if (t == 0) bsum[blockIdx.x] = sh[0];
}

__global__ __launch_bounds__(64) void k_scan_b(int* bsum, int nb, int* row_ptr, int n) {
    if (threadIdx.x == 0 && blockIdx.x == 0) {
        int acc = 0;
        for (int b = 0; b < nb; ++b) { int t = bsum[b]; bsum[b] = acc; acc += t; }
        row_ptr[n] = acc;
    }
}

__global__ __launch_bounds__(256) void k_scan_c(const int* __restrict__ deg,
                                                const int* __restrict__ bsum,
                                                int* __restrict__ row_ptr,
                                                int* __restrict__ cursor, int n) {
    __shared__ int sh[256];
    int base = blockIdx.x * 1024;
    int t = threadIdx.x;
    int v[4];
    int s = 0;
#pragma unroll
    for (int i = 0; i < 4; ++i) {
        int idx = base + t * 4 + i;
        v[i] = (idx < n) ? deg[idx] : 0;
        s += v[i];
    }
    sh[t] = s;
    __syncthreads();
    for (int off = 1; off < 256; off <<= 1) {
        int x = (t >= off) ? sh[t - off] : 0;
        __syncthreads();
        sh[t] += x;
        __syncthreads();
    }
    int excl = sh[t] - s + bsum[blockIdx.x];
#pragma unroll
    for (int i = 0; i < 4; ++i) {
        int idx = base + t * 4 + i;
        if (idx < n) {
            row_ptr[idx] = excl;
            cursor[idx] = excl;
            excl += v[i];
        }
    }
}

// ---------------- CSR fill ----------------
__global__ __launch_bounds__(256) void k_fill(const void* edges, const int* flag,
                                              int E, int* cursor, int* csr) {
    int is64 = *flag;
    for (int e = blockIdx.x * blockDim.x + threadIdx.x; e < E;
         e += gridDim.x * blockDim.x) {
        int s = edge_at(edges, is64, (size_t)e);
        int d = edge_at(edges, is64, (size_t)E + e);
        int pos = atomicAdd(&cursor[d], 1);
        csr[pos] = s;
    }
}

// ---------------- mean aggregation: one wave per node ----------------
template <int D>
__global__ __launch_bounds__(256) void k_agg(const float* __restrict__ x,
                                             const int* __restrict__ row_ptr,
                                             const int* __restrict__ csr,
                                             float* __restrict__ outn, int n) {
    constexpr int V = D / 64;
    int wave = blockIdx.x * (blockDim.x >> 6) + (threadIdx.x >> 6);
    int lane = threadIdx.x & 63;
    if (wave >= n) return;
    int s0 = row_ptr[wave], s1 = row_ptr[wave + 1];
    float acc[V];
#pragma unroll
    for (int i = 0; i < V; ++i) acc[i] = 0.f;
    int e = s0;
    for (; e + 1 < s1; e += 2) {  // 2-edge unroll for ILP
        int sa = csr[e], sb = csr[e + 1];
        const float* pa = x + (size_t)sa * D + lane * V;
        const float* pb = x + (size_t)sb * D + lane * V;
        if (V == 1) {
            float va = pa[0], vb = pb[0];
            acc[0] += va; acc[0] += vb;
        } else {
            float2 va = *reinterpret_cast<const float2*>(pa);
            float2 vb = *reinterpret_cast<const float2*>(pb);
            acc[0] += va.x; acc[1] += va.y;
            acc[0] += vb.x; acc[1] += vb.y;
        }
    }
    if (e < s1) {
        int sa = csr[e];
        const float* pa = x + (size_t)sa * D + lane * V;
        if (V == 1) {
            acc[0] += pa[0];
        } else {
            float2 va = *reinterpret_cast<const float2*>(pa);
            acc[0] += va.x; acc[1] += va.y;
        }
    }
    int cnt = s1 - s0;
    float inv = 1.0f / (float)(cnt > 0 ? cnt : 1);
    float* q = outn + (size_t)wave * D + lane * V;
#pragma unroll
    for (int i = 0; i < V; ++i) q[i] = acc[i] * inv;
}

// ---------------- tiled f32 SIMT GEMM with concat A and activation ----------------
// C[M x NOUT] = act( [A1 | A2] @ W + bias ),  W row-major [K1+K2][NOUT]
// BM=BN=128, BK=16, 256 threads, 8x8 microtile.
template <int K1, int K2, int NOUT, int ACT>
__global__ __launch_bounds__(256) void k_gemm(const float* __restrict__ A1,
                                              const float* __restrict__ A2,
                                              const float* __restrict__ W,
                                              const float* __restrict__ bias,
                                              float* __restrict__ C, int M) {
    constexpr int K = K1 + K2;
    constexpr int BM = 128, BN = 128, BK = 16;
    __shared__ float As[BK][BM + 4];
    __shared__ float Ws[BK][BN];
    int m0 = blockIdx.x * BM;
    int n0 = blockIdx.y * BN;
    int tid = threadIdx.x;
    int tr = tid / 16, tc = tid % 16;
    float acc[8][8];
#pragma unroll
    for (int i = 0; i < 8; ++i)
#pragma unroll
        for (int j = 0; j < 8; ++j) acc[i][j] = 0.f;

    for (int k0 = 0; k0 < K; k0 += BK) {
        // stage A tile (transposed into LDS): 128 rows x 16 cols
#pragma unroll
        for (int i = 0; i < 2; ++i) {
            int slot = tid + i * 256;           // 0..511
            int r = slot >> 2;                  // 0..127
            int c4 = slot & 3;                  // float4 idx in 16 cols
            int row = m0 + r;
            if (row >= M) row = M - 1;
            int kc = k0 + c4 * 4;
            float4 v;
            if (K2 == 0 || kc < K1)
                v = *reinterpret_cast<const float4*>(A1 + (size_t)row * K1 + kc);
            else
                v = *reinterpret_cast<const float4*>(A2 + (size_t)row * K2 + (kc - K1));
            As[c4 * 4 + 0][r] = v.x;
            As[c4 * 4 + 1][r] = v.y;
            As[c4 * 4 + 2][r] = v.z;
            As[c4 * 4 + 3][r] = v.w;
        }
        // stage W tile: 16 rows x 128 cols
#pragma unroll
        for (int i = 0; i < 2; ++i) {
            int slot = tid + i * 256;
            int kr = slot >> 5;                 // 0..15
            int c4 = slot & 31;                 // 32 float4 per row
            float4 v = *reinterpret_cast<const float4*>(
                W + (size_t)(k0 + kr) * NOUT + n0 + c4 * 4);
            *reinterpret_cast<float4*>(&Ws[kr][c4 * 4]) = v;
        }
        __syncthreads();
#pragma unroll
        for (int kk = 0; kk < BK; ++kk) {
            float a[8], b[8];
#pragma unroll
            for (int i = 0; i < 8; ++i) a[i] = As[kk][tr * 8 + i];
#pragma unroll
            for (int j = 0; j < 8; ++j) b[j] = Ws[kk][tc * 8 + j];
#pragma unroll
            for (int i = 0; i < 8; ++i)
#pragma unroll
                for (int j = 0; j < 8; ++j) acc[i][j] += a[i] * b[j];
        }
        __syncthreads();
    }
    // epilogue
#pragma unroll
    for (int i = 0; i < 8; ++i) {
        int row = m0 + tr * 8 + i;
        if (row >= M) continue;
#pragma unroll
        for (int jv = 0; jv < 2; ++jv) {
            float4 v;
            float* vp = &v.x;
#pragma unroll
            for (int u = 0; u < 4; ++u) {
                int j = jv * 4 + u;
                int col = n0 + tc * 8 + j;
                float val = acc[i][j] + bias[col];
                if (ACT == 1) val = 1.0f / (1.0f + expf(-val));   // sigmoid
                if (ACT == 2) val = val > 0.f ? val : 0.f;        // relu
                vp[u] = val;
            }
            *reinterpret_cast<float4*>(C + (size_t)row * NOUT + n0 + tc * 8 + jv * 4) = v;
        }
    }
}

// ---------------- final small GEMM: out[N x 40] = h3[N x 256] @ Wm2 + bm2 ----------------
__global__ __launch_bounds__(256) void k_out(const float* __restrict__ h3,
                                             const float* __restrict__ Wm2,
                                             const float* __restrict__ bm2,
                                             float* __restrict__ out, int M) {
    constexpr int K = 256, NO = 40, BM = 32;
    __shared__ float As[BM][129];      // half-K tile, +1 pad
    __shared__ float Ws[128 * NO];     // half-K of Wm2
    int tid = threadIdx.x;
    int m0 = blockIdx.x * BM;
    int r = tid >> 3;        // 0..31
    int cg = tid & 7;        // 5 cols each
    float acc[5] = {0.f, 0.f, 0.f, 0.f, 0.f};
    for (int kh = 0; kh < 2; ++kh) {
        for (int i = tid; i < BM * 32; i += 256) {  // 32 rows x 32 float4
            int rr = i >> 5, c4 = i & 31;
            int row = m0 + rr;
            if (row >= M) row = M - 1;
            float4 v = *reinterpret_cast<const float4*>(
                h3 + (size_t)row * K + kh * 128 + c4 * 4);
            *reinterpret_cast<float4*>(&As[rr][c4 * 4]) = v;
        }
        for (int i = tid; i < 128 * NO; i += 256) Ws[i] = Wm2[kh * 128 * NO + i];
        __syncthreads();
        for (int k = 0; k < 128; ++k) {
            float a = As[r][k];
#pragma unroll
            for (int j = 0; j < 5; ++j) acc[j] += a * Ws[k * NO + cg * 5 + j];
        }
        __syncthreads();
    }
    int row = m0 + r;
    if (row < M) {
#pragma unroll
        for (int j = 0; j < 5; ++j)
            out[(size_t)row * NO + cg * 5 + j] = acc[j] + bm2[cg * 5 + j];
    }
}

// ---------------- launcher ----------------
extern "C" void kernel_launch(void* const* d_in, const int* in_sizes, int n_in,
                              void* d_out, int out_size, void* d_ws, size_t ws_size,
                              hipStream_t stream) {
    const float* features = (const float*)d_in[0];
    const void* edges     = d_in[1];
    const float* W1  = (const float*)d_in[2];
    const float* b1  = (const float*)d_in[3];
    const float* W2  = (const float*)d_in[4];
    const float* b2  = (const float*)d_in[5];
    const float* Wm1 = (const float*)d_in[6];
    const float* bm1 = (const float*)d_in[7];
    const float* Wm2 = (const float*)d_in[8];
    const float* bm2 = (const float*)d_in[9];
    float* out = (float*)d_out;

    const int n = in_sizes[0] / 64;   // 100000
    const int E = in_sizes[1] / 2;    // 1600000

    // workspace carve (512B aligned)
    size_t off = 0;
    auto carve = [&](size_t bytes) {
        size_t cur = off;
        off += (bytes + 511) & ~(size_t)511;
        return cur;
    };
    char* ws = (char*)d_ws;
    int* deg     = (int*)(ws + carve((size_t)n * 4));
    int* row_ptr = (int*)(ws + carve((size_t)(n + 1) * 4));
    int* cursor  = (int*)(ws + carve((size_t)n * 4));
    int* bsum    = (int*)(ws + carve(1024 * 4));
    int* flag    = (int*)(ws + carve(64));
    int* csr     = (int*)(ws + carve((size_t)E * 4));
    float* neigh1 = (float*)(ws + carve((size_t)n * 64 * 4));
    float* h1     = (float*)(ws + carve((size_t)n * 128 * 4));
    float* neigh2 = (float*)(ws + carve((size_t)n * 128 * 4));
    float* h2     = (float*)(ws + carve((size_t)n * 128 * 4));
    float* h3     = neigh1;  // overlay: neigh1+h1+neigh2 (320 f/node) >= 256 f/node

    const int nb = (n + 1023) / 1024;

    hipMemsetAsync(deg, 0, (size_t)n * 4, stream);
    k_detect<<<1, 64, 0, stream>>>(edges, flag);
    k_hist<<<2048, 256, 0, stream>>>(edges, flag, E, deg);
    k_scan_a<<<nb, 256, 0, stream>>>(deg, bsum, n);
    k_scan_b<<<1, 64, 0, stream>>>(bsum, nb, row_ptr, n);
    k_scan_c<<<nb, 256, 0, stream>>>(deg, bsum, row_ptr, cursor, n);
    k_fill<<<2048, 256, 0, stream>>>(edges, flag, E, cursor, csr);

    const int aggGrid = (n + 3) / 4;           // 4 waves per block
    const int gemmGridM = (n + 127) / 128;

    // layer 1
    k_agg<64><<<aggGrid, 256, 0, stream>>>(features, row_ptr, csr, neigh1, n);
    k_gemm<64, 64, 128, 1><<<dim3(gemmGridM, 1), 256, 0, stream>>>(
        features, neigh1, W1, b1, h1, n);
    // layer 2
    k_agg<128><<<aggGrid, 256, 0, stream>>>(h1, row_ptr, csr, neigh2, n);
    k_gemm<128, 128, 128, 1><<<dim3(gemmGridM, 1), 256, 0, stream>>>(
        h1, neigh2, W2, b2, h2, n);
    // MLP
    k_gemm<128, 0, 256, 2><<<dim3(gemmGridM, 2), 256, 0, stream>>>(
        h2, nullptr, Wm1, bm1, h3, n);
    k_out<<<(n + 31) / 32, 256, 0, stream>>>(h3, Wm2, bm2, out, n);
}

// Round 9
// 714.521 us; speedup vs baseline: 1.2678x; 1.2678x over previous
//
#include <hip/hip_runtime.h>
#include <math.h>

// GraphSAGE bf16-MFMA pipeline: CSR build -> cvt(feat) -> agg1 -> mfma1(sigmoid)
//  -> agg2 -> mfma2(sigmoid) -> mfma_mlp1(relu) -> out-layer (f32 math, bf16 A)
// All hidden activations stored bf16; MFMA accumulates f32.

typedef unsigned short u16;
typedef unsigned int u32;

using frag_ab = __attribute__((ext_vector_type(8))) short;   // 8 bf16 (4 VGPR)
using frag_cd = __attribute__((ext_vector_type(4))) float;   // 4 f32

__device__ __forceinline__ float b2f(u16 u) { return __uint_as_float(((u32)u) << 16); }
__device__ __forceinline__ u16 f2b(float f) {              // round-to-nearest-even
    u32 u = __float_as_uint(f);
    u += 0x7fffu + ((u >> 16) & 1u);
    return (u16)(u >> 16);
}

// ---------------- edge dtype probe (int32 vs int64) ----------------
__global__ __launch_bounds__(64) void k_detect(const void* edges, int* flag) {
    if (threadIdx.x == 0 && blockIdx.x == 0) {
        const int* w = (const int*)edges;
        int o = 0;
        for (int i = 1; i < 128; i += 2) o |= w[i];
        *flag = (o == 0) ? 1 : 0;
    }
}

__device__ __forceinline__ int edge_at(const void* p, int is64, size_t idx) {
    return is64 ? (int)((const long long*)p)[idx] : ((const int*)p)[idx];
}

// ---------------- degree histogram ----------------
__global__ __launch_bounds__(256) void k_hist(const void* edges, const int* flag,
                                              int E, int* deg) {
    int is64 = *flag;
    for (int e = blockIdx.x * blockDim.x + threadIdx.x; e < E;
         e += gridDim.x * blockDim.x) {
        int d = edge_at(edges, is64, (size_t)E + e);
        atomicAdd(&deg[d], 1);
    }
}

// ---------------- exclusive scan (3 kernels) ----------------
__global__ __launch_bounds__(256) void k_scan_a(const int* __restrict__ deg,
                                                int* __restrict__ bsum, int n) {
    __shared__ int sh[256];
    int base = blockIdx.x * 1024;
    int t = threadIdx.x;
    int s = 0;
#pragma unroll
    for (int i = 0; i < 4; ++i) {
        int idx = base + t * 4 + i;
        if (idx < n) s += deg[idx];
    }
    sh[t] = s;
    __syncthreads();
    for (int off = 128; off > 0; off >>= 1) {
        if (t < off) sh[t] += sh[t + off];
        __syncthreads();
    }
    if (t == 0) bsum[blockIdx.x] = sh[0];
}

__global__ __launch_bounds__(64) void k_scan_b(int* bsum, int nb, int* row_ptr, int n) {
    if (threadIdx.x == 0 && blockIdx.x == 0) {
        int acc = 0;
        for (int b = 0; b < nb; ++b) { int t = bsum[b]; bsum[b] = acc; acc += t; }
        row_ptr[n] = acc;
    }
}

__global__ __launch_bounds__(256) void k_scan_c(const int* __restrict__ deg,
                                                const int* __restrict__ bsum,
                                                int* __restrict__ row_ptr,
                                                int* __restrict__ cursor, int n) {
    __shared__ int sh[256];
    int base = blockIdx.x * 1024;
    int t = threadIdx.x;
    int v[4];
    int s = 0;
#pragma unroll
    for (int i = 0; i < 4; ++i) {
        int idx = base + t * 4 + i;
        v[i] = (idx < n) ? deg[idx] : 0;
        s += v[i];
    }
    sh[t] = s;
    __syncthreads();
    for (int off = 1; off < 256; off <<= 1) {
        int x = (t >= off) ? sh[t - off] : 0;
        __syncthreads();
        sh[t] += x;
        __syncthreads();
    }
    int excl = sh[t] - s + bsum[blockIdx.x];
#pragma unroll
    for (int i = 0; i < 4; ++i) {
        int idx = base + t * 4 + i;
        if (idx < n) {
            row_ptr[idx] = excl;
            cursor[idx] = excl;
            excl += v[i];
        }
    }
}

// ---------------- CSR fill ----------------
__global__ __launch_bounds__(256) void k_fill(const void* edges, const int* flag,
                                              int E, int* cursor, int* csr) {
    int is64 = *flag;
    for (int e = blockIdx.x * blockDim.x + threadIdx.x; e < E;
         e += gridDim.x * blockDim.x) {
        int s = edge_at(edges, is64, (size_t)e);
        int d = edge_at(edges, is64, (size_t)E + e);
        int pos = atomicAdd(&cursor[d], 1);
        csr[pos] = s;
    }
}

// ---------------- f32 -> bf16 conversion (cnt4 float4 groups) ----------------
__global__ __launch_bounds__(256) void k_cvt(const float* __restrict__ in,
                                             u16* __restrict__ out, int cnt4) {
    int i = blockIdx.x * blockDim.x + threadIdx.x;
    if (i < cnt4) {
        float4 v = reinterpret_cast<const float4*>(in)[i];
        ushort4 o;
        o.x = f2b(v.x); o.y = f2b(v.y); o.z = f2b(v.z); o.w = f2b(v.w);
        reinterpret_cast<ushort4*>(out)[i] = o;
    }
}

// ---------------- bf16 mean aggregation: one wave per node ----------------
template <int D>
__global__ __launch_bounds__(256) void k_agg16(const u16* __restrict__ x,
                                               const int* __restrict__ row_ptr,
                                               const int* __restrict__ csr,
                                               u16* __restrict__ outn, int n) {
    constexpr int V = D / 64;
    int node = blockIdx.x * 4 + (threadIdx.x >> 6);
    int lane = threadIdx.x & 63;
    if (node >= n) return;
    int s0 = row_ptr[node], s1 = row_ptr[node + 1];
    float acc[V];
#pragma unroll
    for (int i = 0; i < V; ++i) acc[i] = 0.f;
    int e = s0;
    for (; e + 1 < s1; e += 2) {
        int sa = csr[e], sb = csr[e + 1];
        if (V == 1) {
            u16 ua = x[(size_t)sa * 64 + lane];
            u16 ub = x[(size_t)sb * 64 + lane];
            acc[0] += b2f(ua);
            acc[0] += b2f(ub);
        } else {
            u32 ua = *reinterpret_cast<const u32*>(x + (size_t)sa * 128 + lane * 2);
            u32 ub = *reinterpret_cast<const u32*>(x + (size_t)sb * 128 + lane * 2);
            acc[0] += b2f((u16)ua); acc[1] += b2f((u16)(ua >> 16));
            acc[0] += b2f((u16)ub); acc[1] += b2f((u16)(ub >> 16));
        }
    }
    if (e < s1) {
        int sa = csr[e];
        if (V == 1) {
            acc[0] += b2f(x[(size_t)sa * 64 + lane]);
        } else {
            u32 ua = *reinterpret_cast<const u32*>(x + (size_t)sa * 128 + lane * 2);
            acc[0] += b2f((u16)ua); acc[1] += b2f((u16)(ua >> 16));
        }
    }
    int cnt = s1 - s0;
    float inv = 1.0f / (float)(cnt > 0 ? cnt : 1);
    if (V == 1) {
        outn[(size_t)node * 64 + lane] = f2b(acc[0] * inv);
    } else {
        u32 o = (u32)f2b(acc[0] * inv) | ((u32)f2b(acc[1] * inv) << 16);
        *reinterpret_cast<u32*>(outn + (size_t)node * 128 + lane * 2) = o;
    }
}

// ---------------- bf16 MFMA GEMM ----------------
// C[:, n0:n0+128] = act([A1|A2] @ W[:, n0:n0+128] + bias)  (bf16 in/out, f32 accum)
// A row-major bf16 (K1 / K2 cols); W row-major f32 [K][NT]; C bf16 [M][NT].
// Block: 256 thr = 4 waves (2x2 of 64x64 tiles) -> 128x128 output.
// W staged in LDS transposed (col-major) with XOR-16B swizzle; A-frags loaded
// direct global->VGPR (each A row used by exactly one block along N<=128 panel).
// ACT: 1=sigmoid, 2=relu.
template <int K1, int K2, int NT, int ACT>
__global__ __launch_bounds__(256) void k_gemm16(const u16* __restrict__ A1,
                                                const u16* __restrict__ A2,
                                                const float* __restrict__ W,
                                                const float* __restrict__ bias,
                                                u16* __restrict__ C, int M) {
    constexpr int K = K1 + K2;
    __shared__ u16 Wt[128 * K];          // [col][k], swizzled
    const int tid = threadIdx.x;
    const int m0 = blockIdx.x * 128;
    const int n0 = blockIdx.y * 128;

    // stage Wt: thread handles (col, k-pair); coalesced f32 reads of W rows
    for (int idx = tid; idx < K * 64; idx += 256) {
        int c = idx & 127;
        int kp = idx >> 7;               // pair index, k = 2*kp
        float w0 = W[(size_t)(2 * kp) * NT + n0 + c];
        float w1 = W[(size_t)(2 * kp + 1) * NT + n0 + c];
        u32 pk = (u32)f2b(w0) | ((u32)f2b(w1) << 16);
        int byte = c * (K * 2) + kp * 4;
        byte ^= (c & 7) << 4;            // same XOR as read side
        *reinterpret_cast<u32*>(reinterpret_cast<char*>(Wt) + byte) = pk;
    }
    __syncthreads();

    const int wid = tid >> 6, lane = tid & 63;
    const int wr = (wid >> 1) * 64;      // wave row offset: 0 or 64
    const int wc = (wid & 1) * 64;       // wave col offset: 0 or 64
    const int lr = lane & 15;            // row (A) / col (B) within 16-tile
    const int lk = (lane >> 4) * 8;      // k-run start within 32-k step

    frag_cd acc[4][4];
#pragma unroll
    for (int mt = 0; mt < 4; ++mt)
#pragma unroll
        for (int nt = 0; nt < 4; ++nt)
            acc[mt][nt] = (frag_cd){0.f, 0.f, 0.f, 0.f};

#pragma unroll 4
    for (int k0 = 0; k0 < K; k0 += 32) {
        const int k = k0 + lk;
        frag_ab b[4];
#pragma unroll
        for (int nt = 0; nt < 4; ++nt) {
            int c = wc + nt * 16 + lr;
            int byte = c * (K * 2) + k * 2;
            byte ^= (c & 7) << 4;
            b[nt] = *reinterpret_cast<const frag_ab*>(
                reinterpret_cast<const char*>(Wt) + byte);
        }
        frag_ab a[4];
#pragma unroll
        for (int mt = 0; mt < 4; ++mt) {
            int r = m0 + wr + mt * 16 + lr;
            if (r >= M) r = M - 1;
            const u16* p = (K2 == 0 || k < K1)
                               ? (A1 + (size_t)r * K1 + k)
                               : (A2 + (size_t)r * K2 + (k - K1));
            a[mt] = *reinterpret_cast<const frag_ab*>(p);
        }
#pragma unroll
        for (int mt = 0; mt < 4; ++mt)
#pragma unroll
            for (int nt = 0; nt < 4; ++nt)
                acc[mt][nt] = __builtin_amdgcn_mfma_f32_16x16x32_bf16(
                    a[mt], b[nt], acc[mt][nt], 0, 0, 0);
    }

    // epilogue: bias + activation, bf16 store
    // C/D layout (m89-verified): col = lane&15, row = (lane>>4)*4 + reg
    const int orow = (lane >> 4) * 4;
#pragma unroll
    for (int mt = 0; mt < 4; ++mt) {
#pragma unroll
        for (int nt = 0; nt < 4; ++nt) {
            int col = n0 + wc + nt * 16 + lr;
            float bb = bias[col];
#pragma unroll
            for (int r = 0; r < 4; ++r) {
                int row = m0 + wr + mt * 16 + orow + r;
                if (row < M) {
                    float v = acc[mt][nt][r] + bb;
                    if (ACT == 1) v = 1.0f / (1.0f + __expf(-v));
                    else if (ACT == 2) v = v > 0.f ? v : 0.f;
                    C[(size_t)row * NT + col] = f2b(v);
                }
            }
        }
    }
}

// ---------------- final layer: out[N x 40] = h3_bf16[N x 256] @ Wm2 + bm2 ----------------
__global__ __launch_bounds__(256) void k_out(const u16* __restrict__ h3,
                                             const float* __restrict__ Wm2,
                                             const float* __restrict__ bm2,
                                             float* __restrict__ out, int M) {
    constexpr int K = 256, NO = 40, BM = 32;
    __shared__ float As[BM][129];
    __shared__ float Ws[128 * NO];
    int tid = threadIdx.x;
    int m0 = blockIdx.x * BM;
    int r = tid >> 3;
    int cg = tid & 7;
    float acc[5] = {0.f, 0.f, 0.f, 0.f, 0.f};
    for (int kh = 0; kh < 2; ++kh) {
        for (int i = tid; i < BM * 64; i += 256) {   // 32 rows x 64 u32 (2 bf16 each)
            int rr = i >> 6, j2 = i & 63;
            int row = m0 + rr;
            if (row >= M) row = M - 1;
            u32 u = *reinterpret_cast<const u32*>(h3 + (size_t)row * K + kh * 128 + j2 * 2);
            As[rr][j2 * 2] = b2f((u16)u);
            As[rr][j2 * 2 + 1] = b2f((u16)(u >> 16));
        }
        for (int i = tid; i < 128 * NO; i += 256) Ws[i] = Wm2[kh * 128 * NO + i];
        __syncthreads();
        for (int k = 0; k < 128; ++k) {
            float a = As[r][k];
#pragma unroll
            for (int j = 0; j < 5; ++j) acc[j] += a * Ws[k * NO + cg * 5 + j];
        }
        __syncthreads();
    }
    int row = m0 + r;
    if (row < M) {
#pragma unroll
        for (int j = 0; j < 5; ++j)
            out[(size_t)row * NO + cg * 5 + j] = acc[j] + bm2[cg * 5 + j];
    }
}

// ---------------- launcher ----------------
extern "C" void kernel_launch(void* const* d_in, const int* in_sizes, int n_in,
                              void* d_out, int out_size, void* d_ws, size_t ws_size,
                              hipStream_t stream) {
    const float* features = (const float*)d_in[0];
    const void* edges     = d_in[1];
    const float* W1  = (const float*)d_in[2];
    const float* b1  = (const float*)d_in[3];
    const float* W2  = (const float*)d_in[4];
    const float* b2  = (const float*)d_in[5];
    const float* Wm1 = (const float*)d_in[6];
    const float* bm1 = (const float*)d_in[7];
    const float* Wm2 = (const float*)d_in[8];
    const float* bm2 = (const float*)d_in[9];
    float* out = (float*)d_out;

    const int n = in_sizes[0] / 64;   // 100000
    const int E = in_sizes[1] / 2;    // 1600000

    size_t off = 0;
    auto carve = [&](size_t bytes) {
        size_t cur = off;
        off += (bytes + 511) & ~(size_t)511;
        return cur;
    };
    char* ws = (char*)d_ws;
    int* deg     = (int*)(ws + carve((size_t)n * 4));
    int* row_ptr = (int*)(ws + carve((size_t)(n + 1) * 4));
    int* cursor  = (int*)(ws + carve((size_t)n * 4));
    int* bsum    = (int*)(ws + carve(1024 * 4));
    int* flag    = (int*)(ws + carve(64));
    int* csr     = (int*)(ws + carve((size_t)E * 4));
    // bf16 activation pool (feat16..neigh2_16 contiguous = 76.8MB; h3 overlays it)
    size_t pool0 = carve((size_t)n * 64 * 2);          // feat16  12.8MB
    u16* feat16   = (u16*)(ws + pool0);
    u16* neigh1_16 = (u16*)(ws + carve((size_t)n * 64 * 2));    // 12.8MB
    u16* h1_16     = (u16*)(ws + carve((size_t)n * 128 * 2));   // 25.6MB
    u16* neigh2_16 = (u16*)(ws + carve((size_t)n * 128 * 2));   // 25.6MB
    u16* h2_16     = (u16*)(ws + carve((size_t)n * 128 * 2));   // 25.6MB
    u16* h3_16     = feat16;   // overlay: needs n*256*2 = 51.2MB <= 76.8MB pool

    const int nb = (n + 1023) / 1024;

    hipMemsetAsync(deg, 0, (size_t)n * 4, stream);
    k_detect<<<1, 64, 0, stream>>>(edges, flag);
    k_hist<<<2048, 256, 0, stream>>>(edges, flag, E, deg);
    k_scan_a<<<nb, 256, 0, stream>>>(deg, bsum, n);
    k_scan_b<<<1, 64, 0, stream>>>(bsum, nb, row_ptr, n);
    k_scan_c<<<nb, 256, 0, stream>>>(deg, bsum, row_ptr, cursor, n);
    k_fill<<<2048, 256, 0, stream>>>(edges, flag, E, cursor, csr);

    const int cnt4 = n * 64 / 4;
    k_cvt<<<(cnt4 + 255) / 256, 256, 0, stream>>>(features, feat16, cnt4);

    const int aggGrid = (n + 3) / 4;
    const int gm = (n + 127) / 128;   // 782

    // layer 1: agg + [feat|neigh] @ W1 -> sigmoid -> h1 (bf16)
    k_agg16<64><<<aggGrid, 256, 0, stream>>>(feat16, row_ptr, csr, neigh1_16, n);
    k_gemm16<64, 64, 128, 1><<<dim3(gm, 1), 256, 0, stream>>>(
        feat16, neigh1_16, W1, b1, h1_16, n);
    // layer 2
    k_agg16<128><<<aggGrid, 256, 0, stream>>>(h1_16, row_ptr, csr, neigh2_16, n);
    k_gemm16<128, 128, 128, 1><<<dim3(gm, 1), 256, 0, stream>>>(
        h1_16, neigh2_16, W2, b2, h2_16, n);
    // MLP hidden: h2 @ Wm1 -> relu -> h3 (bf16), NT=256 via grid.y=2
    k_gemm16<128, 0, 256, 2><<<dim3(gm, 2), 256, 0, stream>>>(
        h2_16, nullptr, Wm1, bm1, h3_16, n);
    // classifier (f32 math)
    k_out<<<(n + 31) / 32, 256, 0, stream>>>(h3_16, Wm2, bm2, out, n);
}

// Round 10
// 570.010 us; speedup vs baseline: 1.5892x; 1.2535x over previous
//
#include <hip/hip_runtime.h>
#include <math.h>

// GraphSAGE bf16-MFMA pipeline, slot-CSR variant:
//   fill_slots (one scatter pass, no hist/scan) -> cvt(feat) -> agg1 -> mfma1
//   -> agg2 -> mfma2 -> mfma_mlp1 -> out-layer (f32 math)
// Degrees ~Poisson(16); CAP=64 slots/node; overflow handled exactly via list.

typedef unsigned short u16;
typedef unsigned int u32;

#define CAP 64

using frag_ab = __attribute__((ext_vector_type(8))) short;   // 8 bf16 (4 VGPR)
using frag_cd = __attribute__((ext_vector_type(4))) float;   // 4 f32

__device__ __forceinline__ float b2f(u16 u) { return __uint_as_float(((u32)u) << 16); }
__device__ __forceinline__ u16 f2b(float f) {              // round-to-nearest-even
    u32 u = __float_as_uint(f);
    u += 0x7fffu + ((u >> 16) & 1u);
    return (u16)(u >> 16);
}

// ---------------- edge dtype probe (int32 vs int64) ----------------
__global__ __launch_bounds__(64) void k_detect(const void* edges, int* flag) {
    if (threadIdx.x == 0 && blockIdx.x == 0) {
        const int* w = (const int*)edges;
        int o = 0;
        for (int i = 1; i < 128; i += 2) o |= w[i];
        *flag = (o == 0) ? 1 : 0;
    }
}

__device__ __forceinline__ int edge_at(const void* p, int is64, size_t idx) {
    return is64 ? (int)((const long long*)p)[idx] : ((const int*)p)[idx];
}

// ---------------- slot-CSR fill: one pass, no hist/scan ----------------
__global__ __launch_bounds__(256) void k_fill_slots(const void* edges,
                                                    const int* flag, int E,
                                                    int* cnt, int* slots,
                                                    int* ovf, int* ovf_cnt) {
    int is64 = *flag;
    for (int e = blockIdx.x * blockDim.x + threadIdx.x; e < E;
         e += gridDim.x * blockDim.x) {
        int s = edge_at(edges, is64, (size_t)e);
        int d = edge_at(edges, is64, (size_t)E + e);
        int pos = atomicAdd(&cnt[d], 1);
        if (pos < CAP) {
            slots[(size_t)d * CAP + pos] = s;
        } else {                         // ~never (P(deg>64) ~ 1e-15), but exact
            int op = atomicAdd(ovf_cnt, 1);
            ovf[2 * op] = d;
            ovf[2 * op + 1] = s;
        }
    }
}

// ---------------- f32 -> bf16 conversion ----------------
__global__ __launch_bounds__(256) void k_cvt(const float* __restrict__ in,
                                             u16* __restrict__ out, int cnt4) {
    int i = blockIdx.x * blockDim.x + threadIdx.x;
    if (i < cnt4) {
        float4 v = reinterpret_cast<const float4*>(in)[i];
        ushort4 o;
        o.x = f2b(v.x); o.y = f2b(v.y); o.z = f2b(v.z); o.w = f2b(v.w);
        reinterpret_cast<ushort4*>(out)[i] = o;
    }
}

// ---------------- bf16 mean aggregation: one wave per node, 4-edge unroll ----
template <int D>
__global__ __launch_bounds__(256) void k_agg16(const u16* __restrict__ x,
                                               const int* __restrict__ cnt,
                                               const int* __restrict__ slots,
                                               const int* __restrict__ ovf,
                                               const int* __restrict__ ovf_cnt,
                                               u16* __restrict__ outn, int n) {
    constexpr int V = D / 64;
    int node = blockIdx.x * 4 + (threadIdx.x >> 6);
    int lane = threadIdx.x & 63;
    if (node >= n) return;
    int c = cnt[node];
    int m = c < CAP ? c : CAP;
    const int* sl = slots + (size_t)node * CAP;
    float acc[V];
#pragma unroll
    for (int i = 0; i < V; ++i) acc[i] = 0.f;

    int e = 0;
    for (; e + 3 < m; e += 4) {          // 4 independent row loads in flight
        int sA = sl[e], sB = sl[e + 1], sC = sl[e + 2], sD = sl[e + 3];
        if (V == 1) {
            float a0 = b2f(x[(size_t)sA * 64 + lane]);
            float a1 = b2f(x[(size_t)sB * 64 + lane]);
            float a2 = b2f(x[(size_t)sC * 64 + lane]);
            float a3 = b2f(x[(size_t)sD * 64 + lane]);
            acc[0] += (a0 + a1) + (a2 + a3);
        } else {
            u32 u0 = *reinterpret_cast<const u32*>(x + (size_t)sA * 128 + lane * 2);
            u32 u1 = *reinterpret_cast<const u32*>(x + (size_t)sB * 128 + lane * 2);
            u32 u2 = *reinterpret_cast<const u32*>(x + (size_t)sC * 128 + lane * 2);
            u32 u3 = *reinterpret_cast<const u32*>(x + (size_t)sD * 128 + lane * 2);
            acc[0] += (b2f((u16)u0) + b2f((u16)u1)) + (b2f((u16)u2) + b2f((u16)u3));
            acc[1] += (b2f((u16)(u0 >> 16)) + b2f((u16)(u1 >> 16))) +
                      (b2f((u16)(u2 >> 16)) + b2f((u16)(u3 >> 16)));
        }
    }
    for (; e < m; ++e) {
        int sA = sl[e];
        if (V == 1) {
            acc[0] += b2f(x[(size_t)sA * 64 + lane]);
        } else {
            u32 u0 = *reinterpret_cast<const u32*>(x + (size_t)sA * 128 + lane * 2);
            acc[0] += b2f((u16)u0);
            acc[1] += b2f((u16)(u0 >> 16));
        }
    }
    if (c > CAP) {                        // exact overflow path (wave-uniform)
        int mo = *ovf_cnt;
        for (int i = 0; i < mo; ++i) {
            if (ovf[2 * i] == node) {
                int sA = ovf[2 * i + 1];
                if (V == 1) {
                    acc[0] += b2f(x[(size_t)sA * 64 + lane]);
                } else {
                    u32 u0 = *reinterpret_cast<const u32*>(x + (size_t)sA * 128 + lane * 2);
                    acc[0] += b2f((u16)u0);
                    acc[1] += b2f((u16)(u0 >> 16));
                }
            }
        }
    }
    float inv = 1.0f / (float)(c > 0 ? c : 1);
    if (V == 1) {
        outn[(size_t)node * 64 + lane] = f2b(acc[0] * inv);
    } else {
        u32 o = (u32)f2b(acc[0] * inv) | ((u32)f2b(acc[1] * inv) << 16);
        *reinterpret_cast<u32*>(outn + (size_t)node * 128 + lane * 2) = o;
    }
}

// ---------------- bf16 MFMA GEMM (unchanged from verified R9 kernel) --------
// C[:, n0:n0+128] = act([A1|A2] @ W[:, n0:n0+128] + bias)  (bf16 in/out, f32 accum)
template <int K1, int K2, int NT, int ACT>
__global__ __launch_bounds__(256) void k_gemm16(const u16* __restrict__ A1,
                                                const u16* __restrict__ A2,
                                                const float* __restrict__ W,
                                                const float* __restrict__ bias,
                                                u16* __restrict__ C, int M) {
    constexpr int K = K1 + K2;
    __shared__ u16 Wt[128 * K];          // [col][k], swizzled
    const int tid = threadIdx.x;
    const int m0 = blockIdx.x * 128;
    const int n0 = blockIdx.y * 128;

    for (int idx = tid; idx < K * 64; idx += 256) {
        int c = idx & 127;
        int kp = idx >> 7;
        float w0 = W[(size_t)(2 * kp) * NT + n0 + c];
        float w1 = W[(size_t)(2 * kp + 1) * NT + n0 + c];
        u32 pk = (u32)f2b(w0) | ((u32)f2b(w1) << 16);
        int byte = c * (K * 2) + kp * 4;
        byte ^= (c & 7) << 4;
        *reinterpret_cast<u32*>(reinterpret_cast<char*>(Wt) + byte) = pk;
    }
    __syncthreads();

    const int wid = tid >> 6, lane = tid & 63;
    const int wr = (wid >> 1) * 64;
    const int wc = (wid & 1) * 64;
    const int lr = lane & 15;
    const int lk = (lane >> 4) * 8;

    frag_cd acc[4][4];
#pragma unroll
    for (int mt = 0; mt < 4; ++mt)
#pragma unroll
        for (int nt = 0; nt < 4; ++nt)
            acc[mt][nt] = (frag_cd){0.f, 0.f, 0.f, 0.f};

#pragma unroll 4
    for (int k0 = 0; k0 < K; k0 += 32) {
        const int k = k0 + lk;
        frag_ab b[4];
#pragma unroll
        for (int nt = 0; nt < 4; ++nt) {
            int c = wc + nt * 16 + lr;
            int byte = c * (K * 2) + k * 2;
            byte ^= (c & 7) << 4;
            b[nt] = *reinterpret_cast<const frag_ab*>(
                reinterpret_cast<const char*>(Wt) + byte);
        }
        frag_ab a[4];
#pragma unroll
        for (int mt = 0; mt < 4; ++mt) {
            int r = m0 + wr + mt * 16 + lr;
            if (r >= M) r = M - 1;
            const u16* p = (K2 == 0 || k < K1)
                               ? (A1 + (size_t)r * K1 + k)
                               : (A2 + (size_t)r * K2 + (k - K1));
            a[mt] = *reinterpret_cast<const frag_ab*>(p);
        }
#pragma unroll
        for (int mt = 0; mt < 4; ++mt)
#pragma unroll
            for (int nt = 0; nt < 4; ++nt)
                acc[mt][nt] = __builtin_amdgcn_mfma_f32_16x16x32_bf16(
                    a[mt], b[nt], acc[mt][nt], 0, 0, 0);
    }

    const int orow = (lane >> 4) * 4;
#pragma unroll
    for (int mt = 0; mt < 4; ++mt) {
#pragma unroll
        for (int nt = 0; nt < 4; ++nt) {
            int col = n0 + wc + nt * 16 + lr;
            float bb = bias[col];
#pragma unroll
            for (int r = 0; r < 4; ++r) {
                int row = m0 + wr + mt * 16 + orow + r;
                if (row < M) {
                    float v = acc[mt][nt][r] + bb;
                    if (ACT == 1) v = 1.0f / (1.0f + __expf(-v));
                    else if (ACT == 2) v = v > 0.f ? v : 0.f;
                    C[(size_t)row * NT + col] = f2b(v);
                }
            }
        }
    }
}

// ---------------- final layer: out[N x 40] = h3_bf16[N x 256] @ Wm2 + bm2 ----
__global__ __launch_bounds__(256) void k_out(const u16* __restrict__ h3,
                                             const float* __restrict__ Wm2,
                                             const float* __restrict__ bm2,
                                             float* __restrict__ out, int M) {
    constexpr int K = 256, NO = 40, BM = 32;
    __shared__ float As[BM][129];
    __shared__ float Ws[128 * NO];
    int tid = threadIdx.x;
    int m0 = blockIdx.x * BM;
    int r = tid >> 3;
    int cg = tid & 7;
    float acc[5] = {0.f, 0.f, 0.f, 0.f, 0.f};
    for (int kh = 0; kh < 2; ++kh) {
        for (int i = tid; i < BM * 64; i += 256) {
            int rr = i >> 6, j2 = i & 63;
            int row = m0 + rr;
            if (row >= M) row = M - 1;
            u32 u = *reinterpret_cast<const u32*>(h3 + (size_t)row * K + kh * 128 + j2 * 2);
            As[rr][j2 * 2] = b2f((u16)u);
            As[rr][j2 * 2 + 1] = b2f((u16)(u >> 16));
        }
        for (int i = tid; i < 128 * NO; i += 256) Ws[i] = Wm2[kh * 128 * NO + i];
        __syncthreads();
        for (int k = 0; k < 128; ++k) {
            float a = As[r][k];
#pragma unroll
            for (int j = 0; j < 5; ++j) acc[j] += a * Ws[k * NO + cg * 5 + j];
        }
        __syncthreads();
    }
    int row = m0 + r;
    if (row < M) {
#pragma unroll
        for (int j = 0; j < 5; ++j)
            out[(size_t)row * NO + cg * 5 + j] = acc[j] + bm2[cg * 5 + j];
    }
}

// ---------------- launcher ----------------
extern "C" void kernel_launch(void* const* d_in, const int* in_sizes, int n_in,
                              void* d_out, int out_size, void* d_ws, size_t ws_size,
                              hipStream_t stream) {
    const float* features = (const float*)d_in[0];
    const void* edges     = d_in[1];
    const float* W1  = (const float*)d_in[2];
    const float* b1  = (const float*)d_in[3];
    const float* W2  = (const float*)d_in[4];
    const float* b2  = (const float*)d_in[5];
    const float* Wm1 = (const float*)d_in[6];
    const float* bm1 = (const float*)d_in[7];
    const float* Wm2 = (const float*)d_in[8];
    const float* bm2 = (const float*)d_in[9];
    float* out = (float*)d_out;

    const int n = in_sizes[0] / 64;   // 100000
    const int E = in_sizes[1] / 2;    // 1600000

    size_t off = 0;
    auto carve = [&](size_t bytes) {
        size_t cur = off;
        off += (bytes + 511) & ~(size_t)511;
        return cur;
    };
    char* ws = (char*)d_ws;
    int* cnt     = (int*)(ws + carve((size_t)n * 4));
    int* flag    = (int*)(ws + carve(64));
    int* ovf_cnt = (int*)(ws + carve(64));
    int* slots   = (int*)(ws + carve((size_t)n * CAP * 4));   // 25.6MB
    int* ovf     = (int*)(ws + carve((size_t)E * 2 * 4));     // 12.8MB (can't overflow)
    // bf16 activation pool (feat16..neigh1 contiguous; h3 overlays feat16..h1)
    u16* feat16    = (u16*)(ws + carve((size_t)n * 64 * 2));    // 12.8MB
    u16* neigh1_16 = (u16*)(ws + carve((size_t)n * 64 * 2));    // 12.8MB
    u16* h1_16     = (u16*)(ws + carve((size_t)n * 128 * 2));   // 25.6MB
    u16* neigh2_16 = (u16*)(ws + carve((size_t)n * 128 * 2));   // 25.6MB
    u16* h2_16     = (u16*)(ws + carve((size_t)n * 128 * 2));   // 25.6MB
    u16* h3_16     = feat16;   // overlay: n*256*2 = 51.2MB over feat+neigh1+h1 (51.2MB)

    hipMemsetAsync(cnt, 0, (size_t)n * 4, stream);
    hipMemsetAsync(ovf_cnt, 0, 4, stream);
    k_detect<<<1, 64, 0, stream>>>(edges, flag);
    k_fill_slots<<<4096, 256, 0, stream>>>(edges, flag, E, cnt, slots, ovf, ovf_cnt);

    const int cnt4 = n * 64 / 4;
    k_cvt<<<(cnt4 + 255) / 256, 256, 0, stream>>>(features, feat16, cnt4);

    const int aggGrid = (n + 3) / 4;
    const int gm = (n + 127) / 128;   // 782

    // layer 1: agg + [feat|neigh] @ W1 -> sigmoid -> h1 (bf16)
    k_agg16<64><<<aggGrid, 256, 0, stream>>>(feat16, cnt, slots, ovf, ovf_cnt,
                                             neigh1_16, n);
    k_gemm16<64, 64, 128, 1><<<dim3(gm, 1), 256, 0, stream>>>(
        feat16, neigh1_16, W1, b1, h1_16, n);
    // layer 2
    k_agg16<128><<<aggGrid, 256, 0, stream>>>(h1_16, cnt, slots, ovf, ovf_cnt,
                                              neigh2_16, n);
    k_gemm16<128, 128, 128, 1><<<dim3(gm, 1), 256, 0, stream>>>(
        h1_16, neigh2_16, W2, b2, h2_16, n);
    // MLP hidden: h2 @ Wm1 -> relu -> h3 (bf16), NT=256 via grid.y=2
    k_gemm16<128, 0, 256, 2><<<dim3(gm, 2), 256, 0, stream>>>(
        h2_16, nullptr, Wm1, bm1, h3_16, n);
    // classifier (f32 math)
    k_out<<<(n + 31) / 32, 256, 0, stream>>>(h3_16, Wm2, bm2, out, n);
}

// Round 11
// 522.276 us; speedup vs baseline: 1.7344x; 1.0914x over previous
//
#include <hip/hip_runtime.h>
#include <math.h>

// GraphSAGE bf16-MFMA pipeline, binned slot-CSR variant:
//   8x fill_bin (dst-binned so slot writes are L2-resident) -> cvt -> agg1
//   -> mfma1 -> agg2 -> mfma2 -> mfma_mlp1 -> out-layer (f32 math)
// CAP=32 slots/node (P(deg>32)~8e-5); exact overflow via list.

typedef unsigned short u16;
typedef unsigned int u32;

#define CAP 32
#define NBINS 8

using frag_ab = __attribute__((ext_vector_type(8))) short;   // 8 bf16 (4 VGPR)
using frag_cd = __attribute__((ext_vector_type(4))) float;   // 4 f32

__device__ __forceinline__ float b2f(u16 u) { return __uint_as_float(((u32)u) << 16); }
__device__ __forceinline__ u16 f2b(float f) {              // round-to-nearest-even
    u32 u = __float_as_uint(f);
    u += 0x7fffu + ((u >> 16) & 1u);
    return (u16)(u >> 16);
}

// ---------------- edge dtype probe (int32 vs int64) ----------------
__global__ __launch_bounds__(64) void k_detect(const void* edges, int* flag) {
    if (threadIdx.x == 0 && blockIdx.x == 0) {
        const int* w = (const int*)edges;
        int o = 0;
        for (int i = 1; i < 128; i += 2) o |= w[i];
        *flag = (o == 0) ? 1 : 0;
    }
}

__device__ __forceinline__ int edge_at(const void* p, int is64, size_t idx) {
    return is64 ? (int)((const long long*)p)[idx] : ((const int*)p)[idx];
}

// ---------------- binned slot fill: pass p handles dst in [lo,hi) ----------
// Slot sub-region for one bin = 12500*32*4B = 1.6MB -> L2-resident writes.
__global__ __launch_bounds__(256) void k_fill_bin(const void* edges,
                                                  const int* flag, int E,
                                                  int lo, int hi,
                                                  int* cnt, int* slots,
                                                  int* ovf, int* ovf_cnt) {
    int is64 = *flag;
    for (int e = blockIdx.x * blockDim.x + threadIdx.x; e < E;
         e += gridDim.x * blockDim.x) {
        int d = edge_at(edges, is64, (size_t)E + e);
        if (d >= lo && d < hi) {
            int s = edge_at(edges, is64, (size_t)e);
            int pos = atomicAdd(&cnt[d], 1);
            if (pos < CAP) {
                slots[(size_t)d * CAP + pos] = s;
            } else {                     // exact overflow path (~8 nodes total)
                int op = atomicAdd(ovf_cnt, 1);
                ovf[2 * op] = d;
                ovf[2 * op + 1] = s;
            }
        }
    }
}

// ---------------- f32 -> bf16 conversion ----------------
__global__ __launch_bounds__(256) void k_cvt(const float* __restrict__ in,
                                             u16* __restrict__ out, int cnt4) {
    int i = blockIdx.x * blockDim.x + threadIdx.x;
    if (i < cnt4) {
        float4 v = reinterpret_cast<const float4*>(in)[i];
        ushort4 o;
        o.x = f2b(v.x); o.y = f2b(v.y); o.z = f2b(v.z); o.w = f2b(v.w);
        reinterpret_cast<ushort4*>(out)[i] = o;
    }
}

// ---------------- bf16 mean aggregation: one wave per node, 8-edge unroll ----
template <int D>
__global__ __launch_bounds__(256) void k_agg16(const u16* __restrict__ x,
                                               const int* __restrict__ cnt,
                                               const int* __restrict__ slots,
                                               const int* __restrict__ ovf,
                                               const int* __restrict__ ovf_cnt,
                                               u16* __restrict__ outn, int n) {
    constexpr int V = D / 64;
    int node = blockIdx.x * 4 + (threadIdx.x >> 6);
    int lane = threadIdx.x & 63;
    if (node >= n) return;
    int c = cnt[node];
    int m = c < CAP ? c : CAP;
    const int* sl = slots + (size_t)node * CAP;
    float acc[V];
#pragma unroll
    for (int i = 0; i < V; ++i) acc[i] = 0.f;

    int e = 0;
    for (; e + 7 < m; e += 8) {          // 8 independent row loads in flight
        int si[8];
#pragma unroll
        for (int j = 0; j < 8; ++j) si[j] = sl[e + j];
        if (V == 1) {
            float a[8];
#pragma unroll
            for (int j = 0; j < 8; ++j) a[j] = b2f(x[(size_t)si[j] * 64 + lane]);
            acc[0] += ((a[0] + a[1]) + (a[2] + a[3])) + ((a[4] + a[5]) + (a[6] + a[7]));
        } else {
            u32 u[8];
#pragma unroll
            for (int j = 0; j < 8; ++j)
                u[j] = *reinterpret_cast<const u32*>(x + (size_t)si[j] * 128 + lane * 2);
            float lo = 0.f, hi = 0.f;
#pragma unroll
            for (int j = 0; j < 8; ++j) {
                lo += b2f((u16)u[j]);
                hi += b2f((u16)(u[j] >> 16));
            }
            acc[0] += lo; acc[1] += hi;
        }
    }
    for (; e + 3 < m; e += 4) {
        int si[4];
#pragma unroll
        for (int j = 0; j < 4; ++j) si[j] = sl[e + j];
        if (V == 1) {
#pragma unroll
            for (int j = 0; j < 4; ++j) acc[0] += b2f(x[(size_t)si[j] * 64 + lane]);
        } else {
#pragma unroll
            for (int j = 0; j < 4; ++j) {
                u32 u0 = *reinterpret_cast<const u32*>(x + (size_t)si[j] * 128 + lane * 2);
                acc[0] += b2f((u16)u0);
                acc[1] += b2f((u16)(u0 >> 16));
            }
        }
    }
    for (; e < m; ++e) {
        int sA = sl[e];
        if (V == 1) {
            acc[0] += b2f(x[(size_t)sA * 64 + lane]);
        } else {
            u32 u0 = *reinterpret_cast<const u32*>(x + (size_t)sA * 128 + lane * 2);
            acc[0] += b2f((u16)u0);
            acc[1] += b2f((u16)(u0 >> 16));
        }
    }
    if (c > CAP) {                        // exact overflow path (wave-uniform)
        int mo = *ovf_cnt;
        for (int i = 0; i < mo; ++i) {
            if (ovf[2 * i] == node) {
                int sA = ovf[2 * i + 1];
                if (V == 1) {
                    acc[0] += b2f(x[(size_t)sA * 64 + lane]);
                } else {
                    u32 u0 = *reinterpret_cast<const u32*>(x + (size_t)sA * 128 + lane * 2);
                    acc[0] += b2f((u16)u0);
                    acc[1] += b2f((u16)(u0 >> 16));
                }
            }
        }
    }
    float inv = 1.0f / (float)(c > 0 ? c : 1);
    if (V == 1) {
        outn[(size_t)node * 64 + lane] = f2b(acc[0] * inv);
    } else {
        u32 o = (u32)f2b(acc[0] * inv) | ((u32)f2b(acc[1] * inv) << 16);
        *reinterpret_cast<u32*>(outn + (size_t)node * 128 + lane * 2) = o;
    }
}

// ---------------- bf16 MFMA GEMM (unchanged, verified R9/R10) ---------------
template <int K1, int K2, int NT, int ACT>
__global__ __launch_bounds__(256) void k_gemm16(const u16* __restrict__ A1,
                                                const u16* __restrict__ A2,
                                                const float* __restrict__ W,
                                                const float* __restrict__ bias,
                                                u16* __restrict__ C, int M) {
    constexpr int K = K1 + K2;
    __shared__ u16 Wt[128 * K];          // [col][k], swizzled
    const int tid = threadIdx.x;
    const int m0 = blockIdx.x * 128;
    const int n0 = blockIdx.y * 128;

    for (int idx = tid; idx < K * 64; idx += 256) {
        int c = idx & 127;
        int kp = idx >> 7;
        float w0 = W[(size_t)(2 * kp) * NT + n0 + c];
        float w1 = W[(size_t)(2 * kp + 1) * NT + n0 + c];
        u32 pk = (u32)f2b(w0) | ((u32)f2b(w1) << 16);
        int byte = c * (K * 2) + kp * 4;
        byte ^= (c & 7) << 4;
        *reinterpret_cast<u32*>(reinterpret_cast<char*>(Wt) + byte) = pk;
    }
    __syncthreads();

    const int wid = tid >> 6, lane = tid & 63;
    const int wr = (wid >> 1) * 64;
    const int wc = (wid & 1) * 64;
    const int lr = lane & 15;
    const int lk = (lane >> 4) * 8;

    frag_cd acc[4][4];
#pragma unroll
    for (int mt = 0; mt < 4; ++mt)
#pragma unroll
        for (int nt = 0; nt < 4; ++nt)
            acc[mt][nt] = (frag_cd){0.f, 0.f, 0.f, 0.f};

#pragma unroll 4
    for (int k0 = 0; k0 < K; k0 += 32) {
        const int k = k0 + lk;
        frag_ab b[4];
#pragma unroll
        for (int nt = 0; nt < 4; ++nt) {
            int c = wc + nt * 16 + lr;
            int byte = c * (K * 2) + k * 2;
            byte ^= (c & 7) << 4;
            b[nt] = *reinterpret_cast<const frag_ab*>(
                reinterpret_cast<const char*>(Wt) + byte);
        }
        frag_ab a[4];
#pragma unroll
        for (int mt = 0; mt < 4; ++mt) {
            int r = m0 + wr + mt * 16 + lr;
            if (r >= M) r = M - 1;
            const u16* p = (K2 == 0 || k < K1)
                               ? (A1 + (size_t)r * K1 + k)
                               : (A2 + (size_t)r * K2 + (k - K1));
            a[mt] = *reinterpret_cast<const frag_ab*>(p);
        }
#pragma unroll
        for (int mt = 0; mt < 4; ++mt)
#pragma unroll
            for (int nt = 0; nt < 4; ++nt)
                acc[mt][nt] = __builtin_amdgcn_mfma_f32_16x16x32_bf16(
                    a[mt], b[nt], acc[mt][nt], 0, 0, 0);
    }

    const int orow = (lane >> 4) * 4;
#pragma unroll
    for (int mt = 0; mt < 4; ++mt) {
#pragma unroll
        for (int nt = 0; nt < 4; ++nt) {
            int col = n0 + wc + nt * 16 + lr;
            float bb = bias[col];
#pragma unroll
            for (int r = 0; r < 4; ++r) {
                int row = m0 + wr + mt * 16 + orow + r;
                if (row < M) {
                    float v = acc[mt][nt][r] + bb;
                    if (ACT == 1) v = 1.0f / (1.0f + __expf(-v));
                    else if (ACT == 2) v = v > 0.f ? v : 0.f;
                    C[(size_t)row * NT + col] = f2b(v);
                }
            }
        }
    }
}

// ---------------- final layer: out[N x 40] = h3_bf16[N x 256] @ Wm2 + bm2 ----
__global__ __launch_bounds__(256) void k_out(const u16* __restrict__ h3,
                                             const float* __restrict__ Wm2,
                                             const float* __restrict__ bm2,
                                             float* __restrict__ out, int M) {
    constexpr int K = 256, NO = 40, BM = 32;
    __shared__ float As[BM][129];
    __shared__ float Ws[128 * NO];
    int tid = threadIdx.x;
    int m0 = blockIdx.x * BM;
    int r = tid >> 3;
    int cg = tid & 7;
    float acc[5] = {0.f, 0.f, 0.f, 0.f, 0.f};
    for (int kh = 0; kh < 2; ++kh) {
        for (int i = tid; i < BM * 64; i += 256) {
            int rr = i >> 6, j2 = i & 63;
            int row = m0 + rr;
            if (row >= M) row = M - 1;
            u32 u = *reinterpret_cast<const u32*>(h3 + (size_t)row * K + kh * 128 + j2 * 2);
            As[rr][j2 * 2] = b2f((u16)u);
            As[rr][j2 * 2 + 1] = b2f((u16)(u >> 16));
        }
        for (int i = tid; i < 128 * NO; i += 256) Ws[i] = Wm2[kh * 128 * NO + i];
        __syncthreads();
        for (int k = 0; k < 128; ++k) {
            float a = As[r][k];
#pragma unroll
            for (int j = 0; j < 5; ++j) acc[j] += a * Ws[k * NO + cg * 5 + j];
        }
        __syncthreads();
    }
    int row = m0 + r;
    if (row < M) {
#pragma unroll
        for (int j = 0; j < 5; ++j)
            out[(size_t)row * NO + cg * 5 + j] = acc[j] + bm2[cg * 5 + j];
    }
}

// ---------------- launcher ----------------
extern "C" void kernel_launch(void* const* d_in, const int* in_sizes, int n_in,
                              void* d_out, int out_size, void* d_ws, size_t ws_size,
                              hipStream_t stream) {
    const float* features = (const float*)d_in[0];
    const void* edges     = d_in[1];
    const float* W1  = (const float*)d_in[2];
    const float* b1  = (const float*)d_in[3];
    const float* W2  = (const float*)d_in[4];
    const float* b2  = (const float*)d_in[5];
    const float* Wm1 = (const float*)d_in[6];
    const float* bm1 = (const float*)d_in[7];
    const float* Wm2 = (const float*)d_in[8];
    const float* bm2 = (const float*)d_in[9];
    float* out = (float*)d_out;

    const int n = in_sizes[0] / 64;   // 100000
    const int E = in_sizes[1] / 2;    // 1600000

    size_t off = 0;
    auto carve = [&](size_t bytes) {
        size_t cur = off;
        off += (bytes + 511) & ~(size_t)511;
        return cur;
    };
    char* ws = (char*)d_ws;
    int* cnt     = (int*)(ws + carve((size_t)n * 4));
    int* flag    = (int*)(ws + carve(64));
    int* ovf_cnt = (int*)(ws + carve(64));
    int* slots   = (int*)(ws + carve((size_t)n * CAP * 4));   // 12.8MB
    int* ovf     = (int*)(ws + carve((size_t)E * 2 * 4));     // 12.8MB (can't overflow)
    u16* feat16    = (u16*)(ws + carve((size_t)n * 64 * 2));    // 12.8MB
    u16* neigh1_16 = (u16*)(ws + carve((size_t)n * 64 * 2));    // 12.8MB
    u16* h1_16     = (u16*)(ws + carve((size_t)n * 128 * 2));   // 25.6MB
    u16* neigh2_16 = (u16*)(ws + carve((size_t)n * 128 * 2));   // 25.6MB
    u16* h2_16     = (u16*)(ws + carve((size_t)n * 128 * 2));   // 25.6MB
    u16* h3_16     = feat16;   // overlay: n*256*2 = 51.2MB over feat+neigh1+h1 (51.2MB)

    hipMemsetAsync(cnt, 0, (size_t)n * 4, stream);
    hipMemsetAsync(ovf_cnt, 0, 4, stream);
    k_detect<<<1, 64, 0, stream>>>(edges, flag);

    // binned fill: each pass's slot sub-region (~1.6MB) is L2-resident
    const int binsz = (n + NBINS - 1) / NBINS;
    for (int b = 0; b < NBINS; ++b) {
        int lo = b * binsz;
        int hi = lo + binsz < n ? lo + binsz : n;
        k_fill_bin<<<2048, 256, 0, stream>>>(edges, flag, E, lo, hi,
                                             cnt, slots, ovf, ovf_cnt);
    }

    const int cnt4 = n * 64 / 4;
    k_cvt<<<(cnt4 + 255) / 256, 256, 0, stream>>>(features, feat16, cnt4);

    const int aggGrid = (n + 3) / 4;
    const int gm = (n + 127) / 128;   // 782

    // layer 1: agg + [feat|neigh] @ W1 -> sigmoid -> h1 (bf16)
    k_agg16<64><<<aggGrid, 256, 0, stream>>>(feat16, cnt, slots, ovf, ovf_cnt,
                                             neigh1_16, n);
    k_gemm16<64, 64, 128, 1><<<dim3(gm, 1), 256, 0, stream>>>(
        feat16, neigh1_16, W1, b1, h1_16, n);
    // layer 2
    k_agg16<128><<<aggGrid, 256, 0, stream>>>(h1_16, cnt, slots, ovf, ovf_cnt,
                                              neigh2_16, n);
    k_gemm16<128, 128, 128, 1><<<dim3(gm, 1), 256, 0, stream>>>(
        h1_16, neigh2_16, W2, b2, h2_16, n);
    // MLP hidden: h2 @ Wm1 -> relu -> h3 (bf16), NT=256 via grid.y=2
    k_gemm16<128, 0, 256, 2><<<dim3(gm, 2), 256, 0, stream>>>(
        h2_16, nullptr, Wm1, bm1, h3_16, n);
    // classifier (f32 math)
    k_out<<<(n + 31) / 32, 256, 0, stream>>>(h3_16, Wm2, bm2, out, n);
}

// Round 12
// 468.081 us; speedup vs baseline: 1.9353x; 1.1158x over previous
//
#include <hip/hip_runtime.h>
#include <math.h>

// GraphSAGE bf16-MFMA pipeline, binned slot-CSR + MFMA classifier:
//   8x fill_bin (L2-resident slot writes) -> cvt -> agg1 -> mfma1 -> agg2
//   -> mfma2 -> mfma_mlp1 -> mfma out-layer (f32 out)
// CAP=32 slots/node (P(deg>32)~8e-5); exact overflow via list.

typedef unsigned short u16;
typedef unsigned int u32;

#define CAP 32
#define NBINS 8

using frag_ab = __attribute__((ext_vector_type(8))) short;   // 8 bf16 (4 VGPR)
using frag_cd = __attribute__((ext_vector_type(4))) float;   // 4 f32

__device__ __forceinline__ float b2f(u16 u) { return __uint_as_float(((u32)u) << 16); }
__device__ __forceinline__ u16 f2b(float f) {              // round-to-nearest-even
    u32 u = __float_as_uint(f);
    u += 0x7fffu + ((u >> 16) & 1u);
    return (u16)(u >> 16);
}

// ---------------- edge dtype probe (int32 vs int64) ----------------
__global__ __launch_bounds__(64) void k_detect(const void* edges, int* flag) {
    if (threadIdx.x == 0 && blockIdx.x == 0) {
        const int* w = (const int*)edges;
        int o = 0;
        for (int i = 1; i < 128; i += 2) o |= w[i];
        *flag = (o == 0) ? 1 : 0;
    }
}

__device__ __forceinline__ int edge_at(const void* p, int is64, size_t idx) {
    return is64 ? (int)((const long long*)p)[idx] : ((const int*)p)[idx];
}

// ---------------- binned slot fill: pass p handles dst in [lo,hi) ----------
__global__ __launch_bounds__(256) void k_fill_bin(const void* edges,
                                                  const int* flag, int E,
                                                  int lo, int hi,
                                                  int* cnt, int* slots,
                                                  int* ovf, int* ovf_cnt) {
    int is64 = *flag;
    for (int e = blockIdx.x * blockDim.x + threadIdx.x; e < E;
         e += gridDim.x * blockDim.x) {
        int d = edge_at(edges, is64, (size_t)E + e);
        if (d >= lo && d < hi) {
            int s = edge_at(edges, is64, (size_t)e);
            int pos = atomicAdd(&cnt[d], 1);
            if (pos < CAP) {
                slots[(size_t)d * CAP + pos] = s;
            } else {                     // exact overflow path (~8 nodes total)
                int op = atomicAdd(ovf_cnt, 1);
                ovf[2 * op] = d;
                ovf[2 * op + 1] = s;
            }
        }
    }
}

// ---------------- f32 -> bf16 conversion ----------------
__global__ __launch_bounds__(256) void k_cvt(const float* __restrict__ in,
                                             u16* __restrict__ out, int cnt4) {
    int i = blockIdx.x * blockDim.x + threadIdx.x;
    if (i < cnt4) {
        float4 v = reinterpret_cast<const float4*>(in)[i];
        ushort4 o;
        o.x = f2b(v.x); o.y = f2b(v.y); o.z = f2b(v.z); o.w = f2b(v.w);
        reinterpret_cast<ushort4*>(out)[i] = o;
    }
}

// ---------------- bf16 mean aggregation: one wave per node, 8-edge unroll ----
template <int D>
__global__ __launch_bounds__(256) void k_agg16(const u16* __restrict__ x,
                                               const int* __restrict__ cnt,
                                               const int* __restrict__ slots,
                                               const int* __restrict__ ovf,
                                               const int* __restrict__ ovf_cnt,
                                               u16* __restrict__ outn, int n) {
    constexpr int V = D / 64;
    int node = blockIdx.x * 4 + (threadIdx.x >> 6);
    int lane = threadIdx.x & 63;
    if (node >= n) return;
    int c = cnt[node];
    int m = c < CAP ? c : CAP;
    const int* sl = slots + (size_t)node * CAP;
    float acc[V];
#pragma unroll
    for (int i = 0; i < V; ++i) acc[i] = 0.f;

    int e = 0;
    for (; e + 7 < m; e += 8) {          // 8 independent row loads in flight
        int si[8];
#pragma unroll
        for (int j = 0; j < 8; ++j) si[j] = sl[e + j];
        if (V == 1) {
            float a[8];
#pragma unroll
            for (int j = 0; j < 8; ++j) a[j] = b2f(x[(size_t)si[j] * 64 + lane]);
            acc[0] += ((a[0] + a[1]) + (a[2] + a[3])) + ((a[4] + a[5]) + (a[6] + a[7]));
        } else {
            u32 u[8];
#pragma unroll
            for (int j = 0; j < 8; ++j)
                u[j] = *reinterpret_cast<const u32*>(x + (size_t)si[j] * 128 + lane * 2);
            float lo = 0.f, hi = 0.f;
#pragma unroll
            for (int j = 0; j < 8; ++j) {
                lo += b2f((u16)u[j]);
                hi += b2f((u16)(u[j] >> 16));
            }
            acc[0] += lo; acc[1] += hi;
        }
    }
    for (; e + 3 < m; e += 4) {
        int si[4];
#pragma unroll
        for (int j = 0; j < 4; ++j) si[j] = sl[e + j];
        if (V == 1) {
#pragma unroll
            for (int j = 0; j < 4; ++j) acc[0] += b2f(x[(size_t)si[j] * 64 + lane]);
        } else {
#pragma unroll
            for (int j = 0; j < 4; ++j) {
                u32 u0 = *reinterpret_cast<const u32*>(x + (size_t)si[j] * 128 + lane * 2);
                acc[0] += b2f((u16)u0);
                acc[1] += b2f((u16)(u0 >> 16));
            }
        }
    }
    for (; e < m; ++e) {
        int sA = sl[e];
        if (V == 1) {
            acc[0] += b2f(x[(size_t)sA * 64 + lane]);
        } else {
            u32 u0 = *reinterpret_cast<const u32*>(x + (size_t)sA * 128 + lane * 2);
            acc[0] += b2f((u16)u0);
            acc[1] += b2f((u16)(u0 >> 16));
        }
    }
    if (c > CAP) {                        // exact overflow path (wave-uniform)
        int mo = *ovf_cnt;
        for (int i = 0; i < mo; ++i) {
            if (ovf[2 * i] == node) {
                int sA = ovf[2 * i + 1];
                if (V == 1) {
                    acc[0] += b2f(x[(size_t)sA * 64 + lane]);
                } else {
                    u32 u0 = *reinterpret_cast<const u32*>(x + (size_t)sA * 128 + lane * 2);
                    acc[0] += b2f((u16)u0);
                    acc[1] += b2f((u16)(u0 >> 16));
                }
            }
        }
    }
    float inv = 1.0f / (float)(c > 0 ? c : 1);
    if (V == 1) {
        outn[(size_t)node * 64 + lane] = f2b(acc[0] * inv);
    } else {
        u32 o = (u32)f2b(acc[0] * inv) | ((u32)f2b(acc[1] * inv) << 16);
        *reinterpret_cast<u32*>(outn + (size_t)node * 128 + lane * 2) = o;
    }
}

// ---------------- bf16 MFMA GEMM (unchanged, verified R9-R11) ---------------
template <int K1, int K2, int NT, int ACT>
__global__ __launch_bounds__(256) void k_gemm16(const u16* __restrict__ A1,
                                                const u16* __restrict__ A2,
                                                const float* __restrict__ W,
                                                const float* __restrict__ bias,
                                                u16* __restrict__ C, int M) {
    constexpr int K = K1 + K2;
    __shared__ u16 Wt[128 * K];          // [col][k], swizzled
    const int tid = threadIdx.x;
    const int m0 = blockIdx.x * 128;
    const int n0 = blockIdx.y * 128;

    for (int idx = tid; idx < K * 64; idx += 256) {
        int c = idx & 127;
        int kp = idx >> 7;
        float w0 = W[(size_t)(2 * kp) * NT + n0 + c];
        float w1 = W[(size_t)(2 * kp + 1) * NT + n0 + c];
        u32 pk = (u32)f2b(w0) | ((u32)f2b(w1) << 16);
        int byte = c * (K * 2) + kp * 4;
        byte ^= (c & 7) << 4;
        *reinterpret_cast<u32*>(reinterpret_cast<char*>(Wt) + byte) = pk;
    }
    __syncthreads();

    const int wid = tid >> 6, lane = tid & 63;
    const int wr = (wid >> 1) * 64;
    const int wc = (wid & 1) * 64;
    const int lr = lane & 15;
    const int lk = (lane >> 4) * 8;

    frag_cd acc[4][4];
#pragma unroll
    for (int mt = 0; mt < 4; ++mt)
#pragma unroll
        for (int nt = 0; nt < 4; ++nt)
            acc[mt][nt] = (frag_cd){0.f, 0.f, 0.f, 0.f};

#pragma unroll 4
    for (int k0 = 0; k0 < K; k0 += 32) {
        const int k = k0 + lk;
        frag_ab b[4];
#pragma unroll
        for (int nt = 0; nt < 4; ++nt) {
            int c = wc + nt * 16 + lr;
            int byte = c * (K * 2) + k * 2;
            byte ^= (c & 7) << 4;
            b[nt] = *reinterpret_cast<const frag_ab*>(
                reinterpret_cast<const char*>(Wt) + byte);
        }
        frag_ab a[4];
#pragma unroll
        for (int mt = 0; mt < 4; ++mt) {
            int r = m0 + wr + mt * 16 + lr;
            if (r >= M) r = M - 1;
            const u16* p = (K2 == 0 || k < K1)
                               ? (A1 + (size_t)r * K1 + k)
                               : (A2 + (size_t)r * K2 + (k - K1));
            a[mt] = *reinterpret_cast<const frag_ab*>(p);
        }
#pragma unroll
        for (int mt = 0; mt < 4; ++mt)
#pragma unroll
            for (int nt = 0; nt < 4; ++nt)
                acc[mt][nt] = __builtin_amdgcn_mfma_f32_16x16x32_bf16(
                    a[mt], b[nt], acc[mt][nt], 0, 0, 0);
    }

    const int orow = (lane >> 4) * 4;
#pragma unroll
    for (int mt = 0; mt < 4; ++mt) {
#pragma unroll
        for (int nt = 0; nt < 4; ++nt) {
            int col = n0 + wc + nt * 16 + lr;
            float bb = bias[col];
#pragma unroll
            for (int r = 0; r < 4; ++r) {
                int row = m0 + wr + mt * 16 + orow + r;
                if (row < M) {
                    float v = acc[mt][nt][r] + bb;
                    if (ACT == 1) v = 1.0f / (1.0f + __expf(-v));
                    else if (ACT == 2) v = v > 0.f ? v : 0.f;
                    C[(size_t)row * NT + col] = f2b(v);
                }
            }
        }
    }
}

// ---------------- MFMA classifier: out[M x 40] f32 = h3 @ Wm2 + bm2 ---------
// 128 rows/block, 4 waves x (2 m-tiles x 3 n-tiles), NT padded 40->48 in LDS.
__global__ __launch_bounds__(256) void k_out16(const u16* __restrict__ h3,
                                               const float* __restrict__ Wm2,
                                               const float* __restrict__ bm2,
                                               float* __restrict__ out, int M) {
    constexpr int K = 256, NO = 40, NP = 48;
    __shared__ u16 Wt[NP * K];           // [col][k] swizzled; cols 40..47 zero
    const int tid = threadIdx.x;
    const int m0 = blockIdx.x * 128;

    for (int idx = tid; idx < NP * (K / 2); idx += 256) {
        int c = idx % NP;
        int kp = idx / NP;
        float w0 = (c < NO) ? Wm2[(size_t)(2 * kp) * NO + c] : 0.f;
        float w1 = (c < NO) ? Wm2[(size_t)(2 * kp + 1) * NO + c] : 0.f;
        u32 pk = (u32)f2b(w0) | ((u32)f2b(w1) << 16);
        int byte = c * (K * 2) + kp * 4;
        byte ^= (c & 7) << 4;
        *reinterpret_cast<u32*>(reinterpret_cast<char*>(Wt) + byte) = pk;
    }
    __syncthreads();

    const int wid = tid >> 6, lane = tid & 63;
    const int wr = wid * 32;             // wave rows: 32 each -> 128
    const int lr = lane & 15;
    const int lk = (lane >> 4) * 8;

    frag_cd acc[2][3];
#pragma unroll
    for (int mt = 0; mt < 2; ++mt)
#pragma unroll
        for (int nt = 0; nt < 3; ++nt)
            acc[mt][nt] = (frag_cd){0.f, 0.f, 0.f, 0.f};

#pragma unroll
    for (int k0 = 0; k0 < K; k0 += 32) {
        const int k = k0 + lk;
        frag_ab b[3];
#pragma unroll
        for (int nt = 0; nt < 3; ++nt) {
            int c = nt * 16 + lr;
            int byte = c * (K * 2) + k * 2;
            byte ^= (c & 7) << 4;
            b[nt] = *reinterpret_cast<const frag_ab*>(
                reinterpret_cast<const char*>(Wt) + byte);
        }
        frag_ab a[2];
#pragma unroll
        for (int mt = 0; mt < 2; ++mt) {
            int r = m0 + wr + mt * 16 + lr;
            if (r >= M) r = M - 1;
            a[mt] = *reinterpret_cast<const frag_ab*>(h3 + (size_t)r * K + k);
        }
#pragma unroll
        for (int mt = 0; mt < 2; ++mt)
#pragma unroll
            for (int nt = 0; nt < 3; ++nt)
                acc[mt][nt] = __builtin_amdgcn_mfma_f32_16x16x32_bf16(
                    a[mt], b[nt], acc[mt][nt], 0, 0, 0);
    }

    const int orow = (lane >> 4) * 4;
#pragma unroll
    for (int mt = 0; mt < 2; ++mt) {
#pragma unroll
        for (int nt = 0; nt < 3; ++nt) {
            int col = nt * 16 + lr;
            if (col < NO) {
                float bb = bm2[col];
#pragma unroll
                for (int r = 0; r < 4; ++r) {
                    int row = m0 + wr + mt * 16 + orow + r;
                    if (row < M)
                        out[(size_t)row * NO + col] = acc[mt][nt][r] + bb;
                }
            }
        }
    }
}

// ---------------- launcher ----------------
extern "C" void kernel_launch(void* const* d_in, const int* in_sizes, int n_in,
                              void* d_out, int out_size, void* d_ws, size_t ws_size,
                              hipStream_t stream) {
    const float* features = (const float*)d_in[0];
    const void* edges     = d_in[1];
    const float* W1  = (const float*)d_in[2];
    const float* b1  = (const float*)d_in[3];
    const float* W2  = (const float*)d_in[4];
    const float* b2  = (const float*)d_in[5];
    const float* Wm1 = (const float*)d_in[6];
    const float* bm1 = (const float*)d_in[7];
    const float* Wm2 = (const float*)d_in[8];
    const float* bm2 = (const float*)d_in[9];
    float* out = (float*)d_out;

    const int n = in_sizes[0] / 64;   // 100000
    const int E = in_sizes[1] / 2;    // 1600000

    size_t off = 0;
    auto carve = [&](size_t bytes) {
        size_t cur = off;
        off += (bytes + 511) & ~(size_t)511;
        return cur;
    };
    char* ws = (char*)d_ws;
    int* cnt     = (int*)(ws + carve((size_t)n * 4));
    int* flag    = (int*)(ws + carve(64));
    int* ovf_cnt = (int*)(ws + carve(64));
    int* slots   = (int*)(ws + carve((size_t)n * CAP * 4));   // 12.8MB
    int* ovf     = (int*)(ws + carve((size_t)E * 2 * 4));     // 12.8MB (can't overflow)
    u16* feat16    = (u16*)(ws + carve((size_t)n * 64 * 2));    // 12.8MB
    u16* neigh1_16 = (u16*)(ws + carve((size_t)n * 64 * 2));    // 12.8MB
    u16* h1_16     = (u16*)(ws + carve((size_t)n * 128 * 2));   // 25.6MB
    u16* neigh2_16 = (u16*)(ws + carve((size_t)n * 128 * 2));   // 25.6MB
    u16* h2_16     = (u16*)(ws + carve((size_t)n * 128 * 2));   // 25.6MB
    u16* h3_16     = feat16;   // overlay: n*256*2 = 51.2MB over feat+neigh1+h1 (51.2MB)

    hipMemsetAsync(cnt, 0, (size_t)n * 4, stream);
    hipMemsetAsync(ovf_cnt, 0, 4, stream);
    k_detect<<<1, 64, 0, stream>>>(edges, flag);

    // binned fill: each pass's slot sub-region (~1.6MB) is L2-resident
    const int binsz = (n + NBINS - 1) / NBINS;
    for (int b = 0; b < NBINS; ++b) {
        int lo = b * binsz;
        int hi = lo + binsz < n ? lo + binsz : n;
        k_fill_bin<<<2048, 256, 0, stream>>>(edges, flag, E, lo, hi,
                                             cnt, slots, ovf, ovf_cnt);
    }

    const int cnt4 = n * 64 / 4;
    k_cvt<<<(cnt4 + 255) / 256, 256, 0, stream>>>(features, feat16, cnt4);

    const int aggGrid = (n + 3) / 4;
    const int gm = (n + 127) / 128;   // 782

    // layer 1: agg + [feat|neigh] @ W1 -> sigmoid -> h1 (bf16)
    k_agg16<64><<<aggGrid, 256, 0, stream>>>(feat16, cnt, slots, ovf, ovf_cnt,
                                             neigh1_16, n);
    k_gemm16<64, 64, 128, 1><<<dim3(gm, 1), 256, 0, stream>>>(
        feat16, neigh1_16, W1, b1, h1_16, n);
    // layer 2
    k_agg16<128><<<aggGrid, 256, 0, stream>>>(h1_16, cnt, slots, ovf, ovf_cnt,
                                              neigh2_16, n);
    k_gemm16<128, 128, 128, 1><<<dim3(gm, 1), 256, 0, stream>>>(
        h1_16, neigh2_16, W2, b2, h2_16, n);
    // MLP hidden: h2 @ Wm1 -> relu -> h3 (bf16), NT=256 via grid.y=2
    k_gemm16<128, 0, 256, 2><<<dim3(gm, 2), 256, 0, stream>>>(
        h2_16, nullptr, Wm1, bm1, h3_16, n);
    // MFMA classifier (f32 out)
    k_out16<<<gm, 256, 0, stream>>>(h3_16, Wm2, bm2, out, n);
}